// Round 5
// baseline (442.870 us; speedup 1.0000x reference)
//
#include <hip/hip_runtime.h>
#include <hip/hip_bf16.h>
#include <hip/hip_fp16.h>

#define B_DIM 8
#define N_DIM 1024
#define C_DIM 768
#define H_DIM 12
#define HD    64
#define M_DIM (B_DIM * N_DIM)   // 8192
#define BH    (B_DIM * H_DIM)   // 96

static constexpr size_t TEN = (size_t)M_DIM * C_DIM;     // 6,291,456
static constexpr size_t WN  = (size_t)C_DIM * C_DIM;     // 589,824

typedef __attribute__((ext_vector_type(8))) short    s16x8;
typedef __attribute__((ext_vector_type(8))) _Float16 f16x8;
typedef __attribute__((ext_vector_type(4))) float    f32x4;

__device__ __forceinline__ unsigned short f2bf(float f) {
    unsigned u = __float_as_uint(f);
    return (unsigned short)((u + 0x7FFFu + ((u >> 16) & 1u)) >> 16);
}
__device__ __forceinline__ float bf2f(unsigned short h) {
    return __uint_as_float(((unsigned)h) << 16);
}
__device__ __forceinline__ unsigned short f2h(float f) {
    __half h = __float2half(f);          // RTN
    return __half_as_ushort(h);
}

// ---------------------------------------------------------------------------
// bf16 hi/lo splits (inputs for the 3-pass GEMMs)
// ---------------------------------------------------------------------------
__global__ __launch_bounds__(256)
void splitX(const float* __restrict__ q, const float* __restrict__ k,
            const float* __restrict__ v, unsigned short* __restrict__ XS)
{
    int t = blockIdx.y;
    const float* src = (t == 0) ? q : (t == 1 ? k : v);
    unsigned short* hi = XS + (size_t)(2 * t) * TEN;
    unsigned short* lo = hi + TEN;
    size_t i = (size_t)blockIdx.x * 256 + threadIdx.x;   // < TEN/8
    float4 v0 = *(const float4*)(src + i * 8);
    float4 v1 = *(const float4*)(src + i * 8 + 4);
    float f[8] = {v0.x, v0.y, v0.z, v0.w, v1.x, v1.y, v1.z, v1.w};
    s16x8 h, l;
    #pragma unroll
    for (int j = 0; j < 8; ++j) {
        unsigned short hh = f2bf(f[j]);
        h[j] = (short)hh;
        l[j] = (short)f2bf(f[j] - bf2f(hh));
    }
    *(s16x8*)(hi + i * 8) = h;
    *(s16x8*)(lo + i * 8) = l;
}

__global__ __launch_bounds__(256)
void splitW(const float* __restrict__ wq, const float* __restrict__ wk,
            const float* __restrict__ wv, const float* __restrict__ wo,
            unsigned short* __restrict__ WS)
{
    int t = blockIdx.y;
    const float* src = (t == 0) ? wq : (t == 1 ? wk : (t == 2 ? wv : wo));
    unsigned short* hi = WS + (size_t)(2 * t) * WN;
    unsigned short* lo = hi + WN;
    size_t i = (size_t)blockIdx.x * 256 + threadIdx.x;   // < WN/8
    float4 v0 = *(const float4*)(src + i * 8);
    float4 v1 = *(const float4*)(src + i * 8 + 4);
    float f[8] = {v0.x, v0.y, v0.z, v0.w, v1.x, v1.y, v1.z, v1.w};
    s16x8 h, l;
    #pragma unroll
    for (int j = 0; j < 8; ++j) {
        unsigned short hh = f2bf(f[j]);
        h[j] = (short)hh;
        l[j] = (short)f2bf(f[j] - bf2f(hh));
    }
    *(s16x8*)(hi + i * 8) = h;
    *(s16x8*)(lo + i * 8) = l;
}

// ---------------------------------------------------------------------------
// cos/sin table: 32 pos x 16 freqs
// ---------------------------------------------------------------------------
__global__ void angles512(float2* __restrict__ tab)
{
    int t = threadIdx.x;
    int pos = t >> 4, j = t & 15;
    float ang = (float)pos * exp2f(-(float)j * 0.41524101186092029f);
    float s, c;
    sincosf(ang, &s, &c);
    tab[t] = make_float2(c, s);
}

// ---------------------------------------------------------------------------
// 3-pass hi/lo bf16 MFMA GEMM, BM=128 BN=128 BK=32, 4 waves (2x2), acc[4][4].
// K' = 3*768: kb 0..23 Ah*Bh, 24..47 Al*Bh, 48..71 Ah*Bl.
// 3-deep LDS pipeline, counted vmcnt(4), raw s_barrier (T3+T4).
// 1D grid, n-fastest decode + XCD chunking for A-panel L2 reuse (T1).
// MODE 1 (QKV, z=0..2): z=0/1 fused RoPE -> fp16 head layout; z=2 fp16 (B,N,C)
// MODE 0 (O-proj): fp32 (B,N,C) + bias -> Of
// ---------------------------------------------------------------------------
template<int MODE>
__global__ __launch_bounds__(256)
void gemm3(const unsigned short* __restrict__ AhQ, const unsigned short* __restrict__ AlQ,
           const unsigned short* __restrict__ AhK, const unsigned short* __restrict__ AlK,
           const unsigned short* __restrict__ AhV, const unsigned short* __restrict__ AlV,
           const unsigned short* __restrict__ WhQ, const unsigned short* __restrict__ WlQ,
           const unsigned short* __restrict__ WhK, const unsigned short* __restrict__ WlK,
           const unsigned short* __restrict__ WhV, const unsigned short* __restrict__ WlV,
           const int* __restrict__ qpos, const int* __restrict__ kpos,
           const float2* __restrict__ tab,
           unsigned short* __restrict__ OQ, unsigned short* __restrict__ OK_,
           unsigned short* __restrict__ OV,
           const float* __restrict__ bias, float* __restrict__ Of)
{
    __shared__ unsigned short sA[3][4][128][8];   // [buf][kslice][m][8]  24KB
    __shared__ unsigned short sB[3][4][128][8];   // [buf][kslice][d][8]  24KB

    const int tid  = threadIdx.x;
    const int lane = tid & 63;
    const int w    = tid >> 6;
    const int wr   = w >> 1, wc = w & 1;
    const int c    = lane & 15, g = lane >> 4;

    // XCD-chunked, n-fastest block decode (gridDim.x % 8 == 0 by construction)
    const int chunk = gridDim.x >> 3;
    const int wgid  = (blockIdx.x & 7) * chunk + (blockIdx.x >> 3);
    int z, m0, n0;
    if (MODE == 1) {
        z = wgid / 384;
        int r = wgid - z * 384;
        m0 = (r / 6) * 128;
        n0 = (r % 6) * 128;
    } else {
        z = 0;
        m0 = (wgid / 6) * 128;
        n0 = (wgid % 6) * 128;
    }

    const unsigned short *Ah, *Al, *Bh, *Bl;
    if (MODE == 0 || z == 0) { Ah = AhQ; Al = AlQ; Bh = WhQ; Bl = WlQ; }
    else if (z == 1)         { Ah = AhK; Al = AlK; Bh = WhK; Bl = WlK; }
    else                     { Ah = AhV; Al = AlV; Bh = WhV; Bl = WlV; }

    f32x4 acc[4][4] = {};

    auto stage = [&](int kb, int buf) {
        int p = kb >= 48 ? 2 : (kb >= 24 ? 1 : 0);
        const unsigned short* Ap = (p == 1) ? Al : Ah;
        const unsigned short* Bp = (p == 2) ? Bl : Bh;
        int ks = (kb - p * 24) * 32;
        #pragma unroll
        for (int t = 0; t < 4; ++t) {
            int is = w * 4 + t;                      // wave-uniform
            if (is < 8) {                            // A: 8 issues
                int gg = is & 3, half = is >> 2;
                const unsigned short* srcp =
                    Ap + (size_t)(m0 + half * 64 + lane) * C_DIM + ks + 8 * gg;
                __builtin_amdgcn_global_load_lds(
                    (const __attribute__((address_space(1))) void*)srcp,
                    (__attribute__((address_space(3))) void*)&sA[buf][gg][half * 64][0],
                    16, 0, 0);
            } else {                                 // B: 8 issues
                int j = is - 8, gg = j & 3, half = j >> 2;
                const unsigned short* srcp =
                    Bp + (size_t)(n0 + half * 64 + lane) * C_DIM + ks + 8 * gg;
                __builtin_amdgcn_global_load_lds(
                    (const __attribute__((address_space(1))) void*)srcp,
                    (__attribute__((address_space(3))) void*)&sB[buf][gg][half * 64][0],
                    16, 0, 0);
            }
        }
    };

    // prologue: fill bufs 0,1; wait for buf 0 only (vmcnt leaves buf1 in flight)
    stage(0, 0);
    stage(1, 1);
    asm volatile("s_waitcnt vmcnt(4)" ::: "memory");
    __builtin_amdgcn_sched_barrier(0);
    __builtin_amdgcn_s_barrier();
    __builtin_amdgcn_sched_barrier(0);

    int cur = 0;
    for (int kb = 0; kb < 72; ++kb) {
        if (kb + 2 < 72)
            stage(kb + 2, (kb + 2) % 3);             // deepen pipeline

        s16x8 a[4], b[4];
        #pragma unroll
        for (int mi = 0; mi < 4; ++mi)
            a[mi] = *(const s16x8*)&sA[cur][g][wr * 64 + 16 * mi + c][0];
        #pragma unroll
        for (int ni = 0; ni < 4; ++ni)
            b[ni] = *(const s16x8*)&sB[cur][g][wc * 64 + 16 * ni + c][0];
        __builtin_amdgcn_s_setprio(1);
        #pragma unroll
        for (int mi = 0; mi < 4; ++mi)
            #pragma unroll
            for (int ni = 0; ni < 4; ++ni)
                acc[mi][ni] = __builtin_amdgcn_mfma_f32_16x16x32_bf16(a[mi], b[ni], acc[mi][ni], 0, 0, 0);
        __builtin_amdgcn_s_setprio(0);

        // wait until next buf's loads landed; keep kb+2's 4 loads in flight
        if (kb + 2 < 72) asm volatile("s_waitcnt vmcnt(4)" ::: "memory");
        else             asm volatile("s_waitcnt vmcnt(0)" ::: "memory");
        __builtin_amdgcn_sched_barrier(0);
        __builtin_amdgcn_s_barrier();
        __builtin_amdgcn_sched_barrier(0);
        cur = (cur == 2) ? 0 : cur + 1;
    }

    if (MODE == 0) {
        #pragma unroll
        for (int ni = 0; ni < 4; ++ni) {
            int d = n0 + wc * 64 + 16 * ni + c;
            float bv = bias[d];
            #pragma unroll
            for (int mi = 0; mi < 4; ++mi)
                #pragma unroll
                for (int r = 0; r < 4; ++r) {
                    int m = m0 + wr * 64 + 16 * mi + 4 * g + r;
                    Of[(size_t)m * C_DIM + d] = acc[mi][ni][r] + bv;
                }
        }
    } else if (z == 2) {
        // V -> fp16 (B,N,C)
        #pragma unroll
        for (int ni = 0; ni < 4; ++ni) {
            int d = n0 + wc * 64 + 16 * ni + c;
            #pragma unroll
            for (int mi = 0; mi < 4; ++mi)
                #pragma unroll
                for (int r = 0; r < 4; ++r) {
                    int m = m0 + wr * 64 + 16 * mi + 4 * g + r;
                    OV[(size_t)m * C_DIM + d] = f2h(acc[mi][ni][r]);
                }
        }
    } else {
        // Q/K: fused RoPE -> fp16 head layout; wave owns one full head (64 d)
        const int* P = z ? kpos : qpos;
        unsigned short* T = z ? OK_ : OQ;
        const float scale = z ? 1.0f : 0.125f;
        const int hh = (n0 >> 6) + wc;
        #pragma unroll
        for (int mi = 0; mi < 4; ++mi)
            #pragma unroll
            for (int r = 0; r < 4; ++r) {
                int m = m0 + wr * 64 + 16 * mi + 4 * g + r;
                int b = m >> 10, n = m & 1023;
                size_t base = ((size_t)(b * H_DIM + hh) * N_DIM + n) * HD;
                #pragma unroll
                for (int bb = 0; bb < 2; ++bb) {
                    int pos = P[2 * m + bb];
                    float2 cs = tab[pos * 16 + c];
                    float x1 = acc[mi][bb * 2 + 0][r];
                    float x2 = acc[mi][bb * 2 + 1][r];
                    float r1 = (x1 * cs.x - x2 * cs.y) * scale;
                    float r2 = (x2 * cs.x + x1 * cs.y) * scale;
                    T[base + bb * 32 + c]      = f2h(r1);
                    T[base + bb * 32 + 16 + c] = f2h(r2);
                }
            }
    }
}

// ---------------------------------------------------------------------------
// V: (B,N,C) fp16 -> V^T (B,H,64,N) fp16
// ---------------------------------------------------------------------------
__global__ __launch_bounds__(256)
void vtrans(const unsigned short* __restrict__ Vf, unsigned short* __restrict__ Vt)
{
    __shared__ unsigned short T[64][72];
    const int bh = blockIdx.y;
    const int nt = blockIdx.x;
    const int tid = threadIdx.x;
    const int b = bh / H_DIM, h = bh % H_DIM;
    const size_t hb = (size_t)bh * (N_DIM * HD);

    #pragma unroll
    for (int it = 0; it < 2; ++it) {
        int f = tid + it * 256;          // 0..511
        int r = f >> 3;                  // n-row 0..63
        int c8 = (f & 7) * 8;            // d 0..56
        s16x8 v = *(const s16x8*)(Vf + ((size_t)(b * N_DIM + nt * 64 + r)) * C_DIM + h * HD + c8);
        #pragma unroll
        for (int j = 0; j < 8; ++j)
            T[c8 + j][r] = (unsigned short)v[j];
    }
    __syncthreads();
    #pragma unroll
    for (int it = 0; it < 2; ++it) {
        int f = tid + it * 256;
        int d = f >> 3;
        int nn = (f & 7) * 8;
        *(s16x8*)(Vt + hb + (size_t)d * N_DIM + nt * 64 + nn) = *(const s16x8*)&T[d][nn];
    }
}

// ---------------------------------------------------------------------------
// fp16 MFMA flash attention. Block = 4 waves, 64 Q-rows, one (b,h). 16 K-tiles.
// Swapped QK^T single-pass fp16; PV fp16. Emits hi/lo bf16 x for the O-GEMM.
// ---------------------------------------------------------------------------
__global__ __launch_bounds__(256)
void attn_f16(const unsigned short* __restrict__ Qh, const unsigned short* __restrict__ Kh,
              const unsigned short* __restrict__ Vt,
              unsigned short* __restrict__ Xbh, unsigned short* __restrict__ Xbl)
{
    __shared__ _Float16 sK[64][72];
    __shared__ _Float16 sV[64][72];
    __shared__ _Float16 sP[4][16][72];

    const int tid  = threadIdx.x;
    const int lane = tid & 63;
    const int wv   = tid >> 6;
    const int c    = lane & 15;
    const int g    = lane >> 4;

    const int bh = blockIdx.y;
    const int q0 = blockIdx.x * 64;
    const size_t hb = (size_t)bh * (N_DIM * HD);

    const size_t qoff = hb + (size_t)(q0 + wv * 16 + c) * HD;
    f16x8 q0f = *(const f16x8*)(Qh + qoff + 8 * g);
    f16x8 q1f = *(const f16x8*)(Qh + qoff + 32 + 8 * g);

    f32x4 acc[4] = {};
    float m_st = -3.0e38f, l_st = 0.0f;

    for (int kt = 0; kt < 16; ++kt) {
        __syncthreads();
        #pragma unroll
        for (int it = 0; it < 2; ++it) {
            int f = tid + it * 256;      // 0..511
            int row = f >> 3;
            int ch = (f & 7) * 8;
            *(s16x8*)&sK[row][ch] = *(const s16x8*)(Kh + hb + (size_t)(kt * 64 + row) * HD + ch);
            *(s16x8*)&sV[row][ch] = *(const s16x8*)(Vt + hb + (size_t)row * N_DIM + kt * 64 + ch);
        }
        __syncthreads();

        // St = K * Q^T single-pass fp16
        f32x4 s[4] = {};
        __builtin_amdgcn_s_setprio(1);
        #pragma unroll
        for (int st = 0; st < 4; ++st) {
            f16x8 a0 = *(const f16x8*)&sK[16 * st + c][8 * g];
            f16x8 a1 = *(const f16x8*)&sK[16 * st + c][32 + 8 * g];
            s[st] = __builtin_amdgcn_mfma_f32_16x16x32_f16(a0, q0f, s[st], 0, 0, 0);
            s[st] = __builtin_amdgcn_mfma_f32_16x16x32_f16(a1, q1f, s[st], 0, 0, 0);
        }
        __builtin_amdgcn_s_setprio(0);

        // online softmax over k (16 vals/lane for q=c; reduce over 4 g-lanes)
        float pm = -3.0e38f;
        #pragma unroll
        for (int st = 0; st < 4; ++st)
            #pragma unroll
            for (int r = 0; r < 4; ++r)
                pm = fmaxf(pm, s[st][r]);
        pm = fmaxf(pm, __shfl_xor(pm, 16, 64));
        pm = fmaxf(pm, __shfl_xor(pm, 32, 64));
        float mnew = fmaxf(m_st, pm);
        float alpha = __expf(m_st - mnew);
        float p[4][4];
        float rs = 0.0f;
        #pragma unroll
        for (int st = 0; st < 4; ++st)
            #pragma unroll
            for (int r = 0; r < 4; ++r) {
                p[st][r] = __expf(s[st][r] - mnew);
                rs += p[st][r];
            }
        rs += __shfl_xor(rs, 16, 64);
        rs += __shfl_xor(rs, 32, 64);
        l_st = alpha * l_st + rs;
        m_st = mnew;
        #pragma unroll
        for (int sd = 0; sd < 4; ++sd)
            acc[sd] *= alpha;

        // P -> fp16 -> wave-private LDS [q=c][k], k = 16st + 4g + r
        #pragma unroll
        for (int st = 0; st < 4; ++st) {
            unsigned w0 = (unsigned)f2h(p[st][0]) | ((unsigned)f2h(p[st][1]) << 16);
            unsigned w1 = (unsigned)f2h(p[st][2]) | ((unsigned)f2h(p[st][3]) << 16);
            *(uint2*)&sP[wv][c][16 * st + 4 * g] = make_uint2(w0, w1);
        }

        // x^T += V^T * P
        __builtin_amdgcn_s_setprio(1);
        #pragma unroll
        for (int m = 0; m < 2; ++m) {
            f16x8 pb = *(const f16x8*)&sP[wv][c][32 * m + 8 * g];
            #pragma unroll
            for (int sd = 0; sd < 4; ++sd) {
                f16x8 va = *(const f16x8*)&sV[16 * sd + c][32 * m + 8 * g];
                acc[sd] = __builtin_amdgcn_mfma_f32_16x16x32_f16(va, pb, acc[sd], 0, 0, 0);
            }
        }
        __builtin_amdgcn_s_setprio(0);
    }

    // normalize + write hi/lo bf16 x in (B,N,C)
    const int b = bh / H_DIM, h = bh % H_DIM;
    const int q = q0 + wv * 16 + c;
    float invl = 1.0f / l_st;
    size_t obase = ((size_t)(b * N_DIM + q)) * C_DIM + h * HD;
    #pragma unroll
    for (int sd = 0; sd < 4; ++sd) {
        unsigned short hs[4], ls[4];
        #pragma unroll
        for (int r = 0; r < 4; ++r) {
            float o = acc[sd][r] * invl;
            hs[r] = f2bf(o);
            ls[r] = f2bf(o - bf2f(hs[r]));
        }
        *(uint2*)(Xbh + obase + 16 * sd + 4 * g) =
            make_uint2((unsigned)hs[0] | ((unsigned)hs[1] << 16),
                       (unsigned)hs[2] | ((unsigned)hs[3] << 16));
        *(uint2*)(Xbl + obase + 16 * sd + 4 * g) =
            make_uint2((unsigned)ls[0] | ((unsigned)ls[1] << 16),
                       (unsigned)ls[2] | ((unsigned)ls[3] << 16));
    }
}

// ---------------------------------------------------------------------------
extern "C" void kernel_launch(void* const* d_in, const int* in_sizes, int n_in,
                              void* d_out, int out_size, void* d_ws, size_t ws_size,
                              hipStream_t stream)
{
    const float* query = (const float*)d_in[0];
    const float* key_  = (const float*)d_in[1];
    const float* value = (const float*)d_in[2];
    const int*   qpos  = (const int*)d_in[3];
    const int*   kpos  = (const int*)d_in[4];
    const float* Wq    = (const float*)d_in[5];
    const float* Wk    = (const float*)d_in[6];
    const float* Wv    = (const float*)d_in[7];
    const float* Wo    = (const float*)d_in[8];
    const float* bo    = (const float*)d_in[9];
    float* out = (float*)d_out;

    unsigned short* XS  = (unsigned short*)d_ws;     // 6 x TEN (bf16 hi/lo q,k,v)
    unsigned short* WS  = XS + 6 * TEN;              // 8 x WN  (bf16 hi/lo Wq..Wo)
    unsigned short* Qh  = WS + 8 * WN;               // fp16 head layout
    unsigned short* Kh  = Qh + TEN;
    unsigned short* Vf  = Kh + TEN;                  // fp16 (B,N,C)
    unsigned short* Vt  = Vf + TEN;                  // fp16 (B,H,64,N)
    unsigned short* Xbh = Vt + TEN;                  // bf16 hi
    unsigned short* Xbl = Xbh + TEN;                 // bf16 lo
    float2* tab = (float2*)(Xbl + TEN);              // 512 float2

    angles512<<<1, 512, 0, stream>>>(tab);
    splitX<<<dim3((unsigned)(TEN / 8 / 256), 3), 256, 0, stream>>>(query, key_, value, XS);
    splitW<<<dim3((unsigned)(WN / 8 / 256), 4), 256, 0, stream>>>(Wq, Wk, Wv, Wo, WS);

    gemm3<1><<<dim3(1152), 256, 0, stream>>>(
        XS + 0 * TEN, XS + 1 * TEN, XS + 2 * TEN, XS + 3 * TEN, XS + 4 * TEN, XS + 5 * TEN,
        WS + 0 * WN, WS + 1 * WN, WS + 2 * WN, WS + 3 * WN, WS + 4 * WN, WS + 5 * WN,
        qpos, kpos, tab, Qh, Kh, Vf, nullptr, nullptr);

    vtrans<<<dim3(N_DIM / 64, BH), 256, 0, stream>>>(Vf, Vt);

    attn_f16<<<dim3(N_DIM / 64, BH), 256, 0, stream>>>(Qh, Kh, Vt, Xbh, Xbl);

    gemm3<0><<<dim3(384), 256, 0, stream>>>(
        Xbh, Xbl, nullptr, nullptr, nullptr, nullptr,
        WS + 6 * WN, WS + 7 * WN, nullptr, nullptr, nullptr, nullptr,
        nullptr, nullptr, nullptr, nullptr, nullptr, nullptr, bo, out);
}

// Round 6
// 331.752 us; speedup vs baseline: 1.3349x; 1.3349x over previous
//
#include <hip/hip_runtime.h>
#include <hip/hip_bf16.h>
#include <hip/hip_fp16.h>

#define B_DIM 8
#define N_DIM 1024
#define C_DIM 768
#define H_DIM 12
#define HD    64
#define M_DIM (B_DIM * N_DIM)   // 8192
#define BH    (B_DIM * H_DIM)   // 96

static constexpr size_t TEN = (size_t)M_DIM * C_DIM;     // 6,291,456
static constexpr size_t WN  = (size_t)C_DIM * C_DIM;     // 589,824

typedef __attribute__((ext_vector_type(8))) short    s16x8;
typedef __attribute__((ext_vector_type(8))) _Float16 f16x8;
typedef __attribute__((ext_vector_type(4))) float    f32x4;

__device__ __forceinline__ unsigned short f2bf(float f) {
    unsigned u = __float_as_uint(f);
    return (unsigned short)((u + 0x7FFFu + ((u >> 16) & 1u)) >> 16);
}
__device__ __forceinline__ float bf2f(unsigned short h) {
    return __uint_as_float(((unsigned)h) << 16);
}
__device__ __forceinline__ unsigned short f2h(float f) {
    __half h = __float2half(f);          // RTN
    return __half_as_ushort(h);
}

// pk layout for GEMM operands: addr(m,k) = ((((m>>7)*24 + (k>>5))*4 + ((k>>3)&3))*128 + (m&127))*8 + (k&7)
// -> each GEMM staging issue reads a contiguous 1KB (fully-coalesced, 16 lines).

// ---------------------------------------------------------------------------
// hi/lo bf16 split of q/k/v into pk layout. Block = one (tensor, panel, kb).
// Thread reads 64B (16 floats, one full line); writes 2x16B hi + 2x16B lo,
// contiguous across threads for fixed gg.
// ---------------------------------------------------------------------------
__global__ __launch_bounds__(256)
void splitX(const float* __restrict__ q, const float* __restrict__ k,
            const float* __restrict__ v, unsigned short* __restrict__ XS)
{
    const int t  = blockIdx.z;
    const int p  = blockIdx.y;      // 64 panels
    const int kb = blockIdx.x;      // 24
    const float* src = (t == 0) ? q : (t == 1 ? k : v);
    unsigned short* hi = XS + (size_t)(2 * t) * TEN;
    unsigned short* lo = hi + TEN;

    const int mr = threadIdx.x & 127;
    const int gh = threadIdx.x >> 7;          // 0/1
    const float* s = src + ((size_t)(p * 128 + mr)) * C_DIM + kb * 32 + gh * 16;
    float4 v0 = *(const float4*)(s);
    float4 v1 = *(const float4*)(s + 4);
    float4 v2 = *(const float4*)(s + 8);
    float4 v3 = *(const float4*)(s + 12);
    float f[16] = {v0.x,v0.y,v0.z,v0.w, v1.x,v1.y,v1.z,v1.w,
                   v2.x,v2.y,v2.z,v2.w, v3.x,v3.y,v3.z,v3.w};
    #pragma unroll
    for (int gj = 0; gj < 2; ++gj) {
        int gg = gh * 2 + gj;
        s16x8 h8, l8;
        #pragma unroll
        for (int e = 0; e < 8; ++e) {
            float x = f[gj * 8 + e];
            unsigned short hh = f2bf(x);
            h8[e] = (short)hh;
            l8[e] = (short)f2bf(x - bf2f(hh));
        }
        size_t a = ((((size_t)p * 24 + kb) * 4 + gg) * 128 + mr) * 8;
        *(s16x8*)(hi + a) = h8;
        *(s16x8*)(lo + a) = l8;
    }
}

// same for the 4 weight matrices (6 panels each)
__global__ __launch_bounds__(256)
void splitW(const float* __restrict__ wq, const float* __restrict__ wk,
            const float* __restrict__ wv, const float* __restrict__ wo,
            unsigned short* __restrict__ WS)
{
    const int t  = blockIdx.z;
    const int p  = blockIdx.y;      // 6 panels
    const int kb = blockIdx.x;      // 24
    const float* src = (t == 0) ? wq : (t == 1 ? wk : (t == 2 ? wv : wo));
    unsigned short* hi = WS + (size_t)(2 * t) * WN;
    unsigned short* lo = hi + WN;

    const int mr = threadIdx.x & 127;
    const int gh = threadIdx.x >> 7;
    const float* s = src + ((size_t)(p * 128 + mr)) * C_DIM + kb * 32 + gh * 16;
    float4 v0 = *(const float4*)(s);
    float4 v1 = *(const float4*)(s + 4);
    float4 v2 = *(const float4*)(s + 8);
    float4 v3 = *(const float4*)(s + 12);
    float f[16] = {v0.x,v0.y,v0.z,v0.w, v1.x,v1.y,v1.z,v1.w,
                   v2.x,v2.y,v2.z,v2.w, v3.x,v3.y,v3.z,v3.w};
    #pragma unroll
    for (int gj = 0; gj < 2; ++gj) {
        int gg = gh * 2 + gj;
        s16x8 h8, l8;
        #pragma unroll
        for (int e = 0; e < 8; ++e) {
            float x = f[gj * 8 + e];
            unsigned short hh = f2bf(x);
            h8[e] = (short)hh;
            l8[e] = (short)f2bf(x - bf2f(hh));
        }
        size_t a = ((((size_t)p * 24 + kb) * 4 + gg) * 128 + mr) * 8;
        *(s16x8*)(hi + a) = h8;
        *(s16x8*)(lo + a) = l8;
    }
}

// ---------------------------------------------------------------------------
// cos/sin table: 32 pos x 16 freqs
// ---------------------------------------------------------------------------
__global__ void angles512(float2* __restrict__ tab)
{
    int t = threadIdx.x;
    int pos = t >> 4, j = t & 15;
    float ang = (float)pos * exp2f(-(float)j * 0.41524101186092029f);
    float s, c;
    sincosf(ang, &s, &c);
    tab[t] = make_float2(c, s);
}

// ---------------------------------------------------------------------------
// 3-pass hi/lo bf16 MFMA GEMM, BM=128 BN=128 BK=32, 4 waves (2x2), acc[4][4].
// K' = 3*768: kb 0..23 Ah*Bh, 24..47 Al*Bh, 48..71 Ah*Bl.
// Operands in pk layout -> each global_load_lds issue = contiguous 1KB.
// 3-deep LDS pipeline, counted vmcnt(4), raw s_barrier; XCD-chunked 1D grid.
// ---------------------------------------------------------------------------
template<int MODE>
__global__ __launch_bounds__(256)
void gemm3(const unsigned short* __restrict__ AhQ, const unsigned short* __restrict__ AlQ,
           const unsigned short* __restrict__ AhK, const unsigned short* __restrict__ AlK,
           const unsigned short* __restrict__ AhV, const unsigned short* __restrict__ AlV,
           const unsigned short* __restrict__ WhQ, const unsigned short* __restrict__ WlQ,
           const unsigned short* __restrict__ WhK, const unsigned short* __restrict__ WlK,
           const unsigned short* __restrict__ WhV, const unsigned short* __restrict__ WlV,
           const int* __restrict__ qpos, const int* __restrict__ kpos,
           const float2* __restrict__ tab,
           unsigned short* __restrict__ OQ, unsigned short* __restrict__ OK_,
           unsigned short* __restrict__ OV,
           const float* __restrict__ bias, float* __restrict__ Of)
{
    __shared__ unsigned short sA[3][4][128][8];   // [buf][kslice][m][8]  24KB
    __shared__ unsigned short sB[3][4][128][8];   // [buf][kslice][d][8]  24KB

    const int tid  = threadIdx.x;
    const int lane = tid & 63;
    const int w    = tid >> 6;
    const int wr   = w >> 1, wc = w & 1;
    const int c    = lane & 15, g = lane >> 4;

    // XCD-chunked, n-fastest block decode (gridDim.x % 8 == 0 by construction)
    const int chunk = gridDim.x >> 3;
    const int wgid  = (blockIdx.x & 7) * chunk + (blockIdx.x >> 3);
    int z, m0, n0;
    if (MODE == 1) {
        z = wgid / 384;
        int r = wgid - z * 384;
        m0 = (r / 6) * 128;
        n0 = (r % 6) * 128;
    } else {
        z = 0;
        m0 = (wgid / 6) * 128;
        n0 = (wgid % 6) * 128;
    }

    const unsigned short *Ah, *Al, *Bh, *Bl;
    if (MODE == 0 || z == 0) { Ah = AhQ; Al = AlQ; Bh = WhQ; Bl = WlQ; }
    else if (z == 1)         { Ah = AhK; Al = AlK; Bh = WhK; Bl = WlK; }
    else                     { Ah = AhV; Al = AlV; Bh = WhV; Bl = WlV; }

    f32x4 acc[4][4] = {};

    auto stage = [&](int kb, int buf) {
        int pp = kb >= 48 ? 2 : (kb >= 24 ? 1 : 0);
        const unsigned short* Ap = (pp == 1) ? Al : Ah;
        const unsigned short* Bp = (pp == 2) ? Bl : Bh;
        int kk = kb - pp * 24;
        const size_t abase = ((size_t)(m0 >> 7) * 24 + kk) * 4096;   // *4*128*8
        const size_t bbase = ((size_t)(n0 >> 7) * 24 + kk) * 4096;
        #pragma unroll
        for (int t = 0; t < 4; ++t) {
            int is = w * 4 + t;                      // wave-uniform
            if (is < 8) {                            // A: 8 issues
                int gg = is & 3, half = is >> 2;
                const unsigned short* srcp =
                    Ap + abase + (size_t)gg * 1024 + (half * 64 + lane) * 8;
                __builtin_amdgcn_global_load_lds(
                    (const __attribute__((address_space(1))) void*)srcp,
                    (__attribute__((address_space(3))) void*)&sA[buf][gg][half * 64][0],
                    16, 0, 0);
            } else {                                 // B: 8 issues
                int j = is - 8, gg = j & 3, half = j >> 2;
                const unsigned short* srcp =
                    Bp + bbase + (size_t)gg * 1024 + (half * 64 + lane) * 8;
                __builtin_amdgcn_global_load_lds(
                    (const __attribute__((address_space(1))) void*)srcp,
                    (__attribute__((address_space(3))) void*)&sB[buf][gg][half * 64][0],
                    16, 0, 0);
            }
        }
    };

    // prologue: fill bufs 0,1; wait for buf 0 only (vmcnt leaves buf1 in flight)
    stage(0, 0);
    stage(1, 1);
    asm volatile("s_waitcnt vmcnt(4)" ::: "memory");
    __builtin_amdgcn_sched_barrier(0);
    __builtin_amdgcn_s_barrier();
    __builtin_amdgcn_sched_barrier(0);

    int cur = 0;
    for (int kb = 0; kb < 72; ++kb) {
        if (kb + 2 < 72)
            stage(kb + 2, (kb + 2) % 3);             // deepen pipeline

        s16x8 a[4], b[4];
        #pragma unroll
        for (int mi = 0; mi < 4; ++mi)
            a[mi] = *(const s16x8*)&sA[cur][g][wr * 64 + 16 * mi + c][0];
        #pragma unroll
        for (int ni = 0; ni < 4; ++ni)
            b[ni] = *(const s16x8*)&sB[cur][g][wc * 64 + 16 * ni + c][0];
        __builtin_amdgcn_s_setprio(1);
        #pragma unroll
        for (int mi = 0; mi < 4; ++mi)
            #pragma unroll
            for (int ni = 0; ni < 4; ++ni)
                acc[mi][ni] = __builtin_amdgcn_mfma_f32_16x16x32_bf16(a[mi], b[ni], acc[mi][ni], 0, 0, 0);
        __builtin_amdgcn_s_setprio(0);

        // wait until next buf's loads landed; keep kb+2's 4 loads in flight
        if (kb + 2 < 72) asm volatile("s_waitcnt vmcnt(4)" ::: "memory");
        else             asm volatile("s_waitcnt vmcnt(0)" ::: "memory");
        __builtin_amdgcn_sched_barrier(0);
        __builtin_amdgcn_s_barrier();
        __builtin_amdgcn_sched_barrier(0);
        cur = (cur == 2) ? 0 : cur + 1;
    }

    if (MODE == 0) {
        #pragma unroll
        for (int ni = 0; ni < 4; ++ni) {
            int d = n0 + wc * 64 + 16 * ni + c;
            float bv = bias[d];
            #pragma unroll
            for (int mi = 0; mi < 4; ++mi)
                #pragma unroll
                for (int r = 0; r < 4; ++r) {
                    int m = m0 + wr * 64 + 16 * mi + 4 * g + r;
                    Of[(size_t)m * C_DIM + d] = acc[mi][ni][r] + bv;
                }
        }
    } else if (z == 2) {
        // V -> fp16 (B,N,C)
        #pragma unroll
        for (int ni = 0; ni < 4; ++ni) {
            int d = n0 + wc * 64 + 16 * ni + c;
            #pragma unroll
            for (int mi = 0; mi < 4; ++mi)
                #pragma unroll
                for (int r = 0; r < 4; ++r) {
                    int m = m0 + wr * 64 + 16 * mi + 4 * g + r;
                    OV[(size_t)m * C_DIM + d] = f2h(acc[mi][ni][r]);
                }
        }
    } else {
        // Q/K: fused RoPE -> fp16 head layout; wave owns one full head (64 d)
        const int* P = z ? kpos : qpos;
        unsigned short* T = z ? OK_ : OQ;
        const float scale = z ? 1.0f : 0.125f;
        const int hh = (n0 >> 6) + wc;
        #pragma unroll
        for (int mi = 0; mi < 4; ++mi)
            #pragma unroll
            for (int r = 0; r < 4; ++r) {
                int m = m0 + wr * 64 + 16 * mi + 4 * g + r;
                int b = m >> 10, n = m & 1023;
                size_t base = ((size_t)(b * H_DIM + hh) * N_DIM + n) * HD;
                #pragma unroll
                for (int bb = 0; bb < 2; ++bb) {
                    int pos = P[2 * m + bb];
                    float2 cs = tab[pos * 16 + c];
                    float x1 = acc[mi][bb * 2 + 0][r];
                    float x2 = acc[mi][bb * 2 + 1][r];
                    float r1 = (x1 * cs.x - x2 * cs.y) * scale;
                    float r2 = (x2 * cs.x + x1 * cs.y) * scale;
                    T[base + bb * 32 + c]      = f2h(r1);
                    T[base + bb * 32 + 16 + c] = f2h(r2);
                }
            }
    }
}

// ---------------------------------------------------------------------------
// V: (B,N,C) fp16 -> V^T (B,H,64,N) fp16
// ---------------------------------------------------------------------------
__global__ __launch_bounds__(256)
void vtrans(const unsigned short* __restrict__ Vf, unsigned short* __restrict__ Vt)
{
    __shared__ unsigned short T[64][72];
    const int bh = blockIdx.y;
    const int nt = blockIdx.x;
    const int tid = threadIdx.x;
    const int b = bh / H_DIM, h = bh % H_DIM;
    const size_t hb = (size_t)bh * (N_DIM * HD);

    #pragma unroll
    for (int it = 0; it < 2; ++it) {
        int f = tid + it * 256;          // 0..511
        int r = f >> 3;                  // n-row 0..63
        int c8 = (f & 7) * 8;            // d 0..56
        s16x8 v = *(const s16x8*)(Vf + ((size_t)(b * N_DIM + nt * 64 + r)) * C_DIM + h * HD + c8);
        #pragma unroll
        for (int j = 0; j < 8; ++j)
            T[c8 + j][r] = (unsigned short)v[j];
    }
    __syncthreads();
    #pragma unroll
    for (int it = 0; it < 2; ++it) {
        int f = tid + it * 256;
        int d = f >> 3;
        int nn = (f & 7) * 8;
        *(s16x8*)(Vt + hb + (size_t)d * N_DIM + nt * 64 + nn) = *(const s16x8*)&T[d][nn];
    }
}

// ---------------------------------------------------------------------------
// fp16 MFMA flash attention. Emits hi/lo bf16 x directly in pk layout.
// ---------------------------------------------------------------------------
__global__ __launch_bounds__(256)
void attn_f16(const unsigned short* __restrict__ Qh, const unsigned short* __restrict__ Kh,
              const unsigned short* __restrict__ Vt,
              unsigned short* __restrict__ Xbh, unsigned short* __restrict__ Xbl)
{
    __shared__ _Float16 sK[64][72];
    __shared__ _Float16 sV[64][72];
    __shared__ _Float16 sP[4][16][72];

    const int tid  = threadIdx.x;
    const int lane = tid & 63;
    const int wv   = tid >> 6;
    const int c    = lane & 15;
    const int g    = lane >> 4;

    const int bh = blockIdx.y;
    const int q0 = blockIdx.x * 64;
    const size_t hb = (size_t)bh * (N_DIM * HD);

    const size_t qoff = hb + (size_t)(q0 + wv * 16 + c) * HD;
    f16x8 q0f = *(const f16x8*)(Qh + qoff + 8 * g);
    f16x8 q1f = *(const f16x8*)(Qh + qoff + 32 + 8 * g);

    f32x4 acc[4] = {};
    float m_st = -3.0e38f, l_st = 0.0f;

    for (int kt = 0; kt < 16; ++kt) {
        __syncthreads();
        #pragma unroll
        for (int it = 0; it < 2; ++it) {
            int f = tid + it * 256;      // 0..511
            int row = f >> 3;
            int ch = (f & 7) * 8;
            *(s16x8*)&sK[row][ch] = *(const s16x8*)(Kh + hb + (size_t)(kt * 64 + row) * HD + ch);
            *(s16x8*)&sV[row][ch] = *(const s16x8*)(Vt + hb + (size_t)row * N_DIM + kt * 64 + ch);
        }
        __syncthreads();

        // St = K * Q^T single-pass fp16
        f32x4 s[4] = {};
        __builtin_amdgcn_s_setprio(1);
        #pragma unroll
        for (int st = 0; st < 4; ++st) {
            f16x8 a0 = *(const f16x8*)&sK[16 * st + c][8 * g];
            f16x8 a1 = *(const f16x8*)&sK[16 * st + c][32 + 8 * g];
            s[st] = __builtin_amdgcn_mfma_f32_16x16x32_f16(a0, q0f, s[st], 0, 0, 0);
            s[st] = __builtin_amdgcn_mfma_f32_16x16x32_f16(a1, q1f, s[st], 0, 0, 0);
        }
        __builtin_amdgcn_s_setprio(0);

        // online softmax over k (16 vals/lane for q=c; reduce over 4 g-lanes)
        float pm = -3.0e38f;
        #pragma unroll
        for (int st = 0; st < 4; ++st)
            #pragma unroll
            for (int r = 0; r < 4; ++r)
                pm = fmaxf(pm, s[st][r]);
        pm = fmaxf(pm, __shfl_xor(pm, 16, 64));
        pm = fmaxf(pm, __shfl_xor(pm, 32, 64));
        float mnew = fmaxf(m_st, pm);
        float alpha = __expf(m_st - mnew);
        float p[4][4];
        float rs = 0.0f;
        #pragma unroll
        for (int st = 0; st < 4; ++st)
            #pragma unroll
            for (int r = 0; r < 4; ++r) {
                p[st][r] = __expf(s[st][r] - mnew);
                rs += p[st][r];
            }
        rs += __shfl_xor(rs, 16, 64);
        rs += __shfl_xor(rs, 32, 64);
        l_st = alpha * l_st + rs;
        m_st = mnew;
        #pragma unroll
        for (int sd = 0; sd < 4; ++sd)
            acc[sd] *= alpha;

        // P -> fp16 -> wave-private LDS [q=c][k], k = 16st + 4g + r
        #pragma unroll
        for (int st = 0; st < 4; ++st) {
            unsigned w0 = (unsigned)f2h(p[st][0]) | ((unsigned)f2h(p[st][1]) << 16);
            unsigned w1 = (unsigned)f2h(p[st][2]) | ((unsigned)f2h(p[st][3]) << 16);
            *(uint2*)&sP[wv][c][16 * st + 4 * g] = make_uint2(w0, w1);
        }

        // x^T += V^T * P
        __builtin_amdgcn_s_setprio(1);
        #pragma unroll
        for (int m = 0; m < 2; ++m) {
            f16x8 pb = *(const f16x8*)&sP[wv][c][32 * m + 8 * g];
            #pragma unroll
            for (int sd = 0; sd < 4; ++sd) {
                f16x8 va = *(const f16x8*)&sV[16 * sd + c][32 * m + 8 * g];
                acc[sd] = __builtin_amdgcn_mfma_f32_16x16x32_f16(va, pb, acc[sd], 0, 0, 0);
            }
        }
        __builtin_amdgcn_s_setprio(0);
    }

    // normalize + write hi/lo bf16 x in pk layout for the O-proj GEMM
    const int b = bh / H_DIM, h = bh % H_DIM;
    const int q = q0 + wv * 16 + c;
    float invl = 1.0f / l_st;
    const int m  = b * N_DIM + q;
    const int p_ = m >> 7, mr = m & 127;
    #pragma unroll
    for (int sd = 0; sd < 4; ++sd) {
        int kdim = h * 64 + 16 * sd + 4 * g;
        int kb = kdim >> 5;
        int gg = (kdim >> 3) & 3;
        int e  = kdim & 7;               // 0 or 4
        size_t a = ((((size_t)p_ * 24 + kb) * 4 + gg) * 128 + mr) * 8 + e;
        unsigned short hs[4], ls[4];
        #pragma unroll
        for (int r = 0; r < 4; ++r) {
            float o = acc[sd][r] * invl;
            hs[r] = f2bf(o);
            ls[r] = f2bf(o - bf2f(hs[r]));
        }
        *(uint2*)(Xbh + a) =
            make_uint2((unsigned)hs[0] | ((unsigned)hs[1] << 16),
                       (unsigned)hs[2] | ((unsigned)hs[3] << 16));
        *(uint2*)(Xbl + a) =
            make_uint2((unsigned)ls[0] | ((unsigned)ls[1] << 16),
                       (unsigned)ls[2] | ((unsigned)ls[3] << 16));
    }
}

// ---------------------------------------------------------------------------
extern "C" void kernel_launch(void* const* d_in, const int* in_sizes, int n_in,
                              void* d_out, int out_size, void* d_ws, size_t ws_size,
                              hipStream_t stream)
{
    const float* query = (const float*)d_in[0];
    const float* key_  = (const float*)d_in[1];
    const float* value = (const float*)d_in[2];
    const int*   qpos  = (const int*)d_in[3];
    const int*   kpos  = (const int*)d_in[4];
    const float* Wq    = (const float*)d_in[5];
    const float* Wk    = (const float*)d_in[6];
    const float* Wv    = (const float*)d_in[7];
    const float* Wo    = (const float*)d_in[8];
    const float* bo    = (const float*)d_in[9];
    float* out = (float*)d_out;

    unsigned short* XS  = (unsigned short*)d_ws;     // 6 x TEN (pk hi/lo q,k,v)
    unsigned short* WS  = XS + 6 * TEN;              // 8 x WN  (pk hi/lo Wq..Wo)
    unsigned short* Qh  = WS + 8 * WN;               // fp16 head layout
    unsigned short* Kh  = Qh + TEN;
    unsigned short* Vf  = Kh + TEN;                  // fp16 (B,N,C)
    unsigned short* Vt  = Vf + TEN;                  // fp16 (B,H,64,N)
    unsigned short* Xbh = Vt + TEN;                  // bf16 hi (pk)
    unsigned short* Xbl = Xbh + TEN;                 // bf16 lo (pk)
    float2* tab = (float2*)(Xbl + TEN);              // 512 float2

    angles512<<<1, 512, 0, stream>>>(tab);
    splitX<<<dim3(24, 64, 3), 256, 0, stream>>>(query, key_, value, XS);
    splitW<<<dim3(24, 6, 4), 256, 0, stream>>>(Wq, Wk, Wv, Wo, WS);

    gemm3<1><<<dim3(1152), 256, 0, stream>>>(
        XS + 0 * TEN, XS + 1 * TEN, XS + 2 * TEN, XS + 3 * TEN, XS + 4 * TEN, XS + 5 * TEN,
        WS + 0 * WN, WS + 1 * WN, WS + 2 * WN, WS + 3 * WN, WS + 4 * WN, WS + 5 * WN,
        qpos, kpos, tab, Qh, Kh, Vf, nullptr, nullptr);

    vtrans<<<dim3(N_DIM / 64, BH), 256, 0, stream>>>(Vf, Vt);

    attn_f16<<<dim3(N_DIM / 64, BH), 256, 0, stream>>>(Qh, Kh, Vt, Xbh, Xbl);

    gemm3<0><<<dim3(384), 256, 0, stream>>>(
        Xbh, Xbl, nullptr, nullptr, nullptr, nullptr,
        WS + 6 * WN, WS + 7 * WN, nullptr, nullptr, nullptr, nullptr,
        nullptr, nullptr, nullptr, nullptr, nullptr, nullptr, bo, out);
}

// Round 7
// 300.507 us; speedup vs baseline: 1.4737x; 1.1040x over previous
//
#include <hip/hip_runtime.h>
#include <hip/hip_bf16.h>
#include <hip/hip_fp16.h>

#define B_DIM 8
#define N_DIM 1024
#define C_DIM 768
#define H_DIM 12
#define HD    64
#define M_DIM (B_DIM * N_DIM)   // 8192
#define BH    (B_DIM * H_DIM)   // 96

static constexpr size_t TEN = (size_t)M_DIM * C_DIM;     // 6,291,456
static constexpr size_t WN  = (size_t)C_DIM * C_DIM;     // 589,824

typedef __attribute__((ext_vector_type(8))) short    s16x8;
typedef __attribute__((ext_vector_type(8))) _Float16 f16x8;
typedef __attribute__((ext_vector_type(4))) float    f32x4;

__device__ __forceinline__ unsigned short f2bf(float f) {
    unsigned u = __float_as_uint(f);
    return (unsigned short)((u + 0x7FFFu + ((u >> 16) & 1u)) >> 16);
}
__device__ __forceinline__ float bf2f(unsigned short h) {
    return __uint_as_float(((unsigned)h) << 16);
}
__device__ __forceinline__ unsigned short f2h(float f) {
    __half h = __float2half(f);          // RTN
    return __half_as_ushort(h);
}

// pk layout for GEMM operands: addr(m,k) = ((((m>>7)*24 + (k>>5))*4 + ((k>>3)&3))*128 + (m&127))*8 + (k&7)
// -> each GEMM staging issue reads a contiguous 1KB (fully-coalesced, 16 lines).

// ---------------------------------------------------------------------------
// hi/lo bf16 split of q/k/v into pk layout. Block = one (tensor, panel, kb).
// ---------------------------------------------------------------------------
__global__ __launch_bounds__(256)
void splitX(const float* __restrict__ q, const float* __restrict__ k,
            const float* __restrict__ v, unsigned short* __restrict__ XS)
{
    const int t  = blockIdx.z;
    const int p  = blockIdx.y;      // 64 panels
    const int kb = blockIdx.x;      // 24
    const float* src = (t == 0) ? q : (t == 1 ? k : v);
    unsigned short* hi = XS + (size_t)(2 * t) * TEN;
    unsigned short* lo = hi + TEN;

    const int mr = threadIdx.x & 127;
    const int gh = threadIdx.x >> 7;          // 0/1
    const float* s = src + ((size_t)(p * 128 + mr)) * C_DIM + kb * 32 + gh * 16;
    float4 v0 = *(const float4*)(s);
    float4 v1 = *(const float4*)(s + 4);
    float4 v2 = *(const float4*)(s + 8);
    float4 v3 = *(const float4*)(s + 12);
    float f[16] = {v0.x,v0.y,v0.z,v0.w, v1.x,v1.y,v1.z,v1.w,
                   v2.x,v2.y,v2.z,v2.w, v3.x,v3.y,v3.z,v3.w};
    #pragma unroll
    for (int gj = 0; gj < 2; ++gj) {
        int gg = gh * 2 + gj;
        s16x8 h8, l8;
        #pragma unroll
        for (int e = 0; e < 8; ++e) {
            float x = f[gj * 8 + e];
            unsigned short hh = f2bf(x);
            h8[e] = (short)hh;
            l8[e] = (short)f2bf(x - bf2f(hh));
        }
        size_t a = ((((size_t)p * 24 + kb) * 4 + gg) * 128 + mr) * 8;
        *(s16x8*)(hi + a) = h8;
        *(s16x8*)(lo + a) = l8;
    }
}

// same for the 4 weight matrices (6 panels each)
__global__ __launch_bounds__(256)
void splitW(const float* __restrict__ wq, const float* __restrict__ wk,
            const float* __restrict__ wv, const float* __restrict__ wo,
            unsigned short* __restrict__ WS)
{
    const int t  = blockIdx.z;
    const int p  = blockIdx.y;      // 6 panels
    const int kb = blockIdx.x;      // 24
    const float* src = (t == 0) ? wq : (t == 1 ? wk : (t == 2 ? wv : wo));
    unsigned short* hi = WS + (size_t)(2 * t) * WN;
    unsigned short* lo = hi + WN;

    const int mr = threadIdx.x & 127;
    const int gh = threadIdx.x >> 7;
    const float* s = src + ((size_t)(p * 128 + mr)) * C_DIM + kb * 32 + gh * 16;
    float4 v0 = *(const float4*)(s);
    float4 v1 = *(const float4*)(s + 4);
    float4 v2 = *(const float4*)(s + 8);
    float4 v3 = *(const float4*)(s + 12);
    float f[16] = {v0.x,v0.y,v0.z,v0.w, v1.x,v1.y,v1.z,v1.w,
                   v2.x,v2.y,v2.z,v2.w, v3.x,v3.y,v3.z,v3.w};
    #pragma unroll
    for (int gj = 0; gj < 2; ++gj) {
        int gg = gh * 2 + gj;
        s16x8 h8, l8;
        #pragma unroll
        for (int e = 0; e < 8; ++e) {
            float x = f[gj * 8 + e];
            unsigned short hh = f2bf(x);
            h8[e] = (short)hh;
            l8[e] = (short)f2bf(x - bf2f(hh));
        }
        size_t a = ((((size_t)p * 24 + kb) * 4 + gg) * 128 + mr) * 8;
        *(s16x8*)(hi + a) = h8;
        *(s16x8*)(lo + a) = l8;
    }
}

// ---------------------------------------------------------------------------
// cos/sin table: 32 pos x 16 freqs
// ---------------------------------------------------------------------------
__global__ void angles512(float2* __restrict__ tab)
{
    int t = threadIdx.x;
    int pos = t >> 4, j = t & 15;
    float ang = (float)pos * exp2f(-(float)j * 0.41524101186092029f);
    float s, c;
    sincosf(ang, &s, &c);
    tab[t] = make_float2(c, s);
}

// ---------------------------------------------------------------------------
// 3-pass hi/lo bf16 MFMA GEMM, BM=128 BN=128 BK=32, 4 waves (2x2), acc[4][4].
// K-FOLDED: loop 24 physical K-blocks; per step stage Ah,Al,Bh,Bl once and
// run all 3 compensation passes (hh, lh, hl) = 48 MFMA/wave per barrier.
// Operands in pk layout -> each global_load_lds issue = contiguous 1KB.
// 2-buf LDS (64KB, 2 blocks/CU); stage at top of iter, vmcnt(0)+barrier at end.
// ---------------------------------------------------------------------------
template<int MODE>
__global__ __launch_bounds__(256)
void gemm3(const unsigned short* __restrict__ AhQ, const unsigned short* __restrict__ AlQ,
           const unsigned short* __restrict__ AhK, const unsigned short* __restrict__ AlK,
           const unsigned short* __restrict__ AhV, const unsigned short* __restrict__ AlV,
           const unsigned short* __restrict__ WhQ, const unsigned short* __restrict__ WlQ,
           const unsigned short* __restrict__ WhK, const unsigned short* __restrict__ WlK,
           const unsigned short* __restrict__ WhV, const unsigned short* __restrict__ WlV,
           const int* __restrict__ qpos, const int* __restrict__ kpos,
           const float2* __restrict__ tab,
           unsigned short* __restrict__ OQ, unsigned short* __restrict__ OK_,
           unsigned short* __restrict__ OV,
           const float* __restrict__ bias, float* __restrict__ Of)
{
    __shared__ unsigned short sAh[2][4][128][8];   // 16KB
    __shared__ unsigned short sAl[2][4][128][8];   // 16KB
    __shared__ unsigned short sBh[2][4][128][8];   // 16KB
    __shared__ unsigned short sBl[2][4][128][8];   // 16KB

    const int tid  = threadIdx.x;
    const int lane = tid & 63;
    const int w    = tid >> 6;
    const int wr   = w >> 1, wc = w & 1;
    const int c    = lane & 15, g = lane >> 4;

    // XCD-chunked, n-fastest block decode (gridDim.x % 8 == 0 by construction)
    const int chunk = gridDim.x >> 3;
    const int wgid  = (blockIdx.x & 7) * chunk + (blockIdx.x >> 3);
    int z, m0, n0;
    if (MODE == 1) {
        z = wgid / 384;
        int r = wgid - z * 384;
        m0 = (r / 6) * 128;
        n0 = (r % 6) * 128;
    } else {
        z = 0;
        m0 = (wgid / 6) * 128;
        n0 = (wgid % 6) * 128;
    }

    const unsigned short *Ah, *Al, *Bh, *Bl;
    if (MODE == 0 || z == 0) { Ah = AhQ; Al = AlQ; Bh = WhQ; Bl = WlQ; }
    else if (z == 1)         { Ah = AhK; Al = AlK; Bh = WhK; Bl = WlK; }
    else                     { Ah = AhV; Al = AlV; Bh = WhV; Bl = WlV; }

    f32x4 acc[4][4] = {};

    // stage all 4 panels of physical K-block kb: 32 issues, 8 per wave
    auto stage = [&](int kb, int buf) {
        const size_t abase = ((size_t)(m0 >> 7) * 24 + kb) * 4096;   // *4*128*8
        const size_t bbase = ((size_t)(n0 >> 7) * 24 + kb) * 4096;
        #pragma unroll
        for (int t = 0; t < 8; ++t) {
            int is = w * 8 + t;                      // wave-uniform 0..31
            int sel = is >> 3;                       // 0:Ah 1:Al 2:Bh 3:Bl
            int j   = is & 7;
            int gg  = j & 3, half = j >> 2;
            const unsigned short* base_p =
                (sel == 0) ? Ah : (sel == 1) ? Al : (sel == 2) ? Bh : Bl;
            size_t bb = (sel < 2) ? abase : bbase;
            const unsigned short* srcp =
                base_p + bb + (size_t)gg * 1024 + (half * 64 + lane) * 8;
            unsigned short* dstp =
                (sel == 0) ? &sAh[buf][gg][half * 64][0] :
                (sel == 1) ? &sAl[buf][gg][half * 64][0] :
                (sel == 2) ? &sBh[buf][gg][half * 64][0] :
                             &sBl[buf][gg][half * 64][0];
            __builtin_amdgcn_global_load_lds(
                (const __attribute__((address_space(1))) void*)srcp,
                (__attribute__((address_space(3))) void*)dstp,
                16, 0, 0);
        }
    };

    stage(0, 0);
    asm volatile("s_waitcnt vmcnt(0)" ::: "memory");
    __builtin_amdgcn_sched_barrier(0);
    __builtin_amdgcn_s_barrier();
    __builtin_amdgcn_sched_barrier(0);

    for (int kb = 0; kb < 24; ++kb) {
        int buf = kb & 1;
        if (kb < 23) stage(kb + 1, buf ^ 1);         // hide latency under compute

        s16x8 ah[4], al[4], bh[4], bl[4];
        #pragma unroll
        for (int mi = 0; mi < 4; ++mi) {
            ah[mi] = *(const s16x8*)&sAh[buf][g][wr * 64 + 16 * mi + c][0];
            al[mi] = *(const s16x8*)&sAl[buf][g][wr * 64 + 16 * mi + c][0];
        }
        #pragma unroll
        for (int ni = 0; ni < 4; ++ni) {
            bh[ni] = *(const s16x8*)&sBh[buf][g][wc * 64 + 16 * ni + c][0];
            bl[ni] = *(const s16x8*)&sBl[buf][g][wc * 64 + 16 * ni + c][0];
        }
        __builtin_amdgcn_s_setprio(1);
        #pragma unroll
        for (int mi = 0; mi < 4; ++mi)
            #pragma unroll
            for (int ni = 0; ni < 4; ++ni)
                acc[mi][ni] = __builtin_amdgcn_mfma_f32_16x16x32_bf16(ah[mi], bh[ni], acc[mi][ni], 0, 0, 0);
        #pragma unroll
        for (int mi = 0; mi < 4; ++mi)
            #pragma unroll
            for (int ni = 0; ni < 4; ++ni)
                acc[mi][ni] = __builtin_amdgcn_mfma_f32_16x16x32_bf16(al[mi], bh[ni], acc[mi][ni], 0, 0, 0);
        #pragma unroll
        for (int mi = 0; mi < 4; ++mi)
            #pragma unroll
            for (int ni = 0; ni < 4; ++ni)
                acc[mi][ni] = __builtin_amdgcn_mfma_f32_16x16x32_bf16(ah[mi], bl[ni], acc[mi][ni], 0, 0, 0);
        __builtin_amdgcn_s_setprio(0);

        asm volatile("s_waitcnt vmcnt(0)" ::: "memory");
        __builtin_amdgcn_sched_barrier(0);
        __builtin_amdgcn_s_barrier();
        __builtin_amdgcn_sched_barrier(0);
    }

    if (MODE == 0) {
        #pragma unroll
        for (int ni = 0; ni < 4; ++ni) {
            int d = n0 + wc * 64 + 16 * ni + c;
            float bv = bias[d];
            #pragma unroll
            for (int mi = 0; mi < 4; ++mi)
                #pragma unroll
                for (int r = 0; r < 4; ++r) {
                    int m = m0 + wr * 64 + 16 * mi + 4 * g + r;
                    Of[(size_t)m * C_DIM + d] = acc[mi][ni][r] + bv;
                }
        }
    } else if (z == 2) {
        // V -> fp16 (B,N,C)
        #pragma unroll
        for (int ni = 0; ni < 4; ++ni) {
            int d = n0 + wc * 64 + 16 * ni + c;
            #pragma unroll
            for (int mi = 0; mi < 4; ++mi)
                #pragma unroll
                for (int r = 0; r < 4; ++r) {
                    int m = m0 + wr * 64 + 16 * mi + 4 * g + r;
                    OV[(size_t)m * C_DIM + d] = f2h(acc[mi][ni][r]);
                }
        }
    } else {
        // Q/K: fused RoPE -> fp16 head layout; wave owns one full head (64 d)
        const int* P = z ? kpos : qpos;
        unsigned short* T = z ? OK_ : OQ;
        const float scale = z ? 1.0f : 0.125f;
        const int hh = (n0 >> 6) + wc;
        #pragma unroll
        for (int mi = 0; mi < 4; ++mi)
            #pragma unroll
            for (int r = 0; r < 4; ++r) {
                int m = m0 + wr * 64 + 16 * mi + 4 * g + r;
                int b = m >> 10, n = m & 1023;
                size_t base = ((size_t)(b * H_DIM + hh) * N_DIM + n) * HD;
                #pragma unroll
                for (int bb = 0; bb < 2; ++bb) {
                    int pos = P[2 * m + bb];
                    float2 cs = tab[pos * 16 + c];
                    float x1 = acc[mi][bb * 2 + 0][r];
                    float x2 = acc[mi][bb * 2 + 1][r];
                    float r1 = (x1 * cs.x - x2 * cs.y) * scale;
                    float r2 = (x2 * cs.x + x1 * cs.y) * scale;
                    T[base + bb * 32 + c]      = f2h(r1);
                    T[base + bb * 32 + 16 + c] = f2h(r2);
                }
            }
    }
}

// ---------------------------------------------------------------------------
// V: (B,N,C) fp16 -> V^T (B,H,64,N) fp16
// ---------------------------------------------------------------------------
__global__ __launch_bounds__(256)
void vtrans(const unsigned short* __restrict__ Vf, unsigned short* __restrict__ Vt)
{
    __shared__ unsigned short T[64][72];
    const int bh = blockIdx.y;
    const int nt = blockIdx.x;
    const int tid = threadIdx.x;
    const int b = bh / H_DIM, h = bh % H_DIM;
    const size_t hb = (size_t)bh * (N_DIM * HD);

    #pragma unroll
    for (int it = 0; it < 2; ++it) {
        int f = tid + it * 256;          // 0..511
        int r = f >> 3;                  // n-row 0..63
        int c8 = (f & 7) * 8;            // d 0..56
        s16x8 v = *(const s16x8*)(Vf + ((size_t)(b * N_DIM + nt * 64 + r)) * C_DIM + h * HD + c8);
        #pragma unroll
        for (int j = 0; j < 8; ++j)
            T[c8 + j][r] = (unsigned short)v[j];
    }
    __syncthreads();
    #pragma unroll
    for (int it = 0; it < 2; ++it) {
        int f = tid + it * 256;
        int d = f >> 3;
        int nn = (f & 7) * 8;
        *(s16x8*)(Vt + hb + (size_t)d * N_DIM + nt * 64 + nn) = *(const s16x8*)&T[d][nn];
    }
}

// ---------------------------------------------------------------------------
// fp16 MFMA flash attention. Emits hi/lo bf16 x directly in pk layout.
// ---------------------------------------------------------------------------
__global__ __launch_bounds__(256)
void attn_f16(const unsigned short* __restrict__ Qh, const unsigned short* __restrict__ Kh,
              const unsigned short* __restrict__ Vt,
              unsigned short* __restrict__ Xbh, unsigned short* __restrict__ Xbl)
{
    __shared__ _Float16 sK[64][72];
    __shared__ _Float16 sV[64][72];
    __shared__ _Float16 sP[4][16][72];

    const int tid  = threadIdx.x;
    const int lane = tid & 63;
    const int wv   = tid >> 6;
    const int c    = lane & 15;
    const int g    = lane >> 4;

    const int bh = blockIdx.y;
    const int q0 = blockIdx.x * 64;
    const size_t hb = (size_t)bh * (N_DIM * HD);

    const size_t qoff = hb + (size_t)(q0 + wv * 16 + c) * HD;
    f16x8 q0f = *(const f16x8*)(Qh + qoff + 8 * g);
    f16x8 q1f = *(const f16x8*)(Qh + qoff + 32 + 8 * g);

    f32x4 acc[4] = {};
    float m_st = -3.0e38f, l_st = 0.0f;

    for (int kt = 0; kt < 16; ++kt) {
        __syncthreads();
        #pragma unroll
        for (int it = 0; it < 2; ++it) {
            int f = tid + it * 256;      // 0..511
            int row = f >> 3;
            int ch = (f & 7) * 8;
            *(s16x8*)&sK[row][ch] = *(const s16x8*)(Kh + hb + (size_t)(kt * 64 + row) * HD + ch);
            *(s16x8*)&sV[row][ch] = *(const s16x8*)(Vt + hb + (size_t)row * N_DIM + kt * 64 + ch);
        }
        __syncthreads();

        // St = K * Q^T single-pass fp16
        f32x4 s[4] = {};
        __builtin_amdgcn_s_setprio(1);
        #pragma unroll
        for (int st = 0; st < 4; ++st) {
            f16x8 a0 = *(const f16x8*)&sK[16 * st + c][8 * g];
            f16x8 a1 = *(const f16x8*)&sK[16 * st + c][32 + 8 * g];
            s[st] = __builtin_amdgcn_mfma_f32_16x16x32_f16(a0, q0f, s[st], 0, 0, 0);
            s[st] = __builtin_amdgcn_mfma_f32_16x16x32_f16(a1, q1f, s[st], 0, 0, 0);
        }
        __builtin_amdgcn_s_setprio(0);

        // online softmax over k (16 vals/lane for q=c; reduce over 4 g-lanes)
        float pm = -3.0e38f;
        #pragma unroll
        for (int st = 0; st < 4; ++st)
            #pragma unroll
            for (int r = 0; r < 4; ++r)
                pm = fmaxf(pm, s[st][r]);
        pm = fmaxf(pm, __shfl_xor(pm, 16, 64));
        pm = fmaxf(pm, __shfl_xor(pm, 32, 64));
        float mnew = fmaxf(m_st, pm);
        float alpha = __expf(m_st - mnew);
        float p[4][4];
        float rs = 0.0f;
        #pragma unroll
        for (int st = 0; st < 4; ++st)
            #pragma unroll
            for (int r = 0; r < 4; ++r) {
                p[st][r] = __expf(s[st][r] - mnew);
                rs += p[st][r];
            }
        rs += __shfl_xor(rs, 16, 64);
        rs += __shfl_xor(rs, 32, 64);
        l_st = alpha * l_st + rs;
        m_st = mnew;
        #pragma unroll
        for (int sd = 0; sd < 4; ++sd)
            acc[sd] *= alpha;

        // P -> fp16 -> wave-private LDS [q=c][k], k = 16st + 4g + r
        #pragma unroll
        for (int st = 0; st < 4; ++st) {
            unsigned w0 = (unsigned)f2h(p[st][0]) | ((unsigned)f2h(p[st][1]) << 16);
            unsigned w1 = (unsigned)f2h(p[st][2]) | ((unsigned)f2h(p[st][3]) << 16);
            *(uint2*)&sP[wv][c][16 * st + 4 * g] = make_uint2(w0, w1);
        }

        // x^T += V^T * P
        __builtin_amdgcn_s_setprio(1);
        #pragma unroll
        for (int m = 0; m < 2; ++m) {
            f16x8 pb = *(const f16x8*)&sP[wv][c][32 * m + 8 * g];
            #pragma unroll
            for (int sd = 0; sd < 4; ++sd) {
                f16x8 va = *(const f16x8*)&sV[16 * sd + c][32 * m + 8 * g];
                acc[sd] = __builtin_amdgcn_mfma_f32_16x16x32_f16(va, pb, acc[sd], 0, 0, 0);
            }
        }
        __builtin_amdgcn_s_setprio(0);
    }

    // normalize + write hi/lo bf16 x in pk layout for the O-proj GEMM
    const int b = bh / H_DIM, h = bh % H_DIM;
    const int q = q0 + wv * 16 + c;
    float invl = 1.0f / l_st;
    const int m  = b * N_DIM + q;
    const int p_ = m >> 7, mr = m & 127;
    #pragma unroll
    for (int sd = 0; sd < 4; ++sd) {
        int kdim = h * 64 + 16 * sd + 4 * g;
        int kb = kdim >> 5;
        int gg = (kdim >> 3) & 3;
        int e  = kdim & 7;               // 0 or 4
        size_t a = ((((size_t)p_ * 24 + kb) * 4 + gg) * 128 + mr) * 8 + e;
        unsigned short hs[4], ls[4];
        #pragma unroll
        for (int r = 0; r < 4; ++r) {
            float o = acc[sd][r] * invl;
            hs[r] = f2bf(o);
            ls[r] = f2bf(o - bf2f(hs[r]));
        }
        *(uint2*)(Xbh + a) =
            make_uint2((unsigned)hs[0] | ((unsigned)hs[1] << 16),
                       (unsigned)hs[2] | ((unsigned)hs[3] << 16));
        *(uint2*)(Xbl + a) =
            make_uint2((unsigned)ls[0] | ((unsigned)ls[1] << 16),
                       (unsigned)ls[2] | ((unsigned)ls[3] << 16));
    }
}

// ---------------------------------------------------------------------------
extern "C" void kernel_launch(void* const* d_in, const int* in_sizes, int n_in,
                              void* d_out, int out_size, void* d_ws, size_t ws_size,
                              hipStream_t stream)
{
    const float* query = (const float*)d_in[0];
    const float* key_  = (const float*)d_in[1];
    const float* value = (const float*)d_in[2];
    const int*   qpos  = (const int*)d_in[3];
    const int*   kpos  = (const int*)d_in[4];
    const float* Wq    = (const float*)d_in[5];
    const float* Wk    = (const float*)d_in[6];
    const float* Wv    = (const float*)d_in[7];
    const float* Wo    = (const float*)d_in[8];
    const float* bo    = (const float*)d_in[9];
    float* out = (float*)d_out;

    unsigned short* XS  = (unsigned short*)d_ws;     // 6 x TEN (pk hi/lo q,k,v)
    unsigned short* WS  = XS + 6 * TEN;              // 8 x WN  (pk hi/lo Wq..Wo)
    unsigned short* Qh  = WS + 8 * WN;               // fp16 head layout
    unsigned short* Kh  = Qh + TEN;
    unsigned short* Vf  = Kh + TEN;                  // fp16 (B,N,C)
    unsigned short* Vt  = Vf + TEN;                  // fp16 (B,H,64,N)
    unsigned short* Xbh = Vt + TEN;                  // bf16 hi (pk)
    unsigned short* Xbl = Xbh + TEN;                 // bf16 lo (pk)
    float2* tab = (float2*)(Xbl + TEN);              // 512 float2

    angles512<<<1, 512, 0, stream>>>(tab);
    splitX<<<dim3(24, 64, 3), 256, 0, stream>>>(query, key_, value, XS);
    splitW<<<dim3(24, 6, 4), 256, 0, stream>>>(Wq, Wk, Wv, Wo, WS);

    gemm3<1><<<dim3(1152), 256, 0, stream>>>(
        XS + 0 * TEN, XS + 1 * TEN, XS + 2 * TEN, XS + 3 * TEN, XS + 4 * TEN, XS + 5 * TEN,
        WS + 0 * WN, WS + 1 * WN, WS + 2 * WN, WS + 3 * WN, WS + 4 * WN, WS + 5 * WN,
        qpos, kpos, tab, Qh, Kh, Vf, nullptr, nullptr);

    vtrans<<<dim3(N_DIM / 64, BH), 256, 0, stream>>>(Vf, Vt);

    attn_f16<<<dim3(N_DIM / 64, BH), 256, 0, stream>>>(Qh, Kh, Vt, Xbh, Xbl);

    gemm3<0><<<dim3(384), 256, 0, stream>>>(
        Xbh, Xbl, nullptr, nullptr, nullptr, nullptr,
        WS + 6 * WN, WS + 7 * WN, nullptr, nullptr, nullptr, nullptr,
        nullptr, nullptr, nullptr, nullptr, nullptr, nullptr, bo, out);
}

// Round 8
// 167.104 us; speedup vs baseline: 2.6503x; 1.7983x over previous
//
#include <hip/hip_runtime.h>
#include <hip/hip_bf16.h>
#include <hip/hip_fp16.h>

#define B_DIM 8
#define N_DIM 1024
#define C_DIM 768
#define H_DIM 12
#define HD    64
#define M_DIM (B_DIM * N_DIM)   // 8192
#define BH    (B_DIM * H_DIM)   // 96

static constexpr size_t TEN = (size_t)M_DIM * C_DIM;     // 6,291,456
static constexpr size_t WN  = (size_t)C_DIM * C_DIM;     // 589,824

typedef __attribute__((ext_vector_type(8))) short    s16x8;
typedef __attribute__((ext_vector_type(8))) _Float16 f16x8;
typedef __attribute__((ext_vector_type(4))) float    f32x4;

__device__ __forceinline__ unsigned short f2h(float f) {
    __half h = __float2half(f);          // RTN
    return __half_as_ushort(h);
}

// pk layout: addr(m,k) = ((((m>>7)*24 + (k>>5))*4 + ((k>>3)&3))*128 + (m&127))*8 + (k&7)
// -> each GEMM staging issue (64 lanes x 16B) reads a contiguous 1KB.

// ---------------------------------------------------------------------------
// fp32 -> fp16 pk-layout convert for q/k/v. Block = (kb, panel, tensor).
// ---------------------------------------------------------------------------
__global__ __launch_bounds__(256)
void convX(const float* __restrict__ q, const float* __restrict__ k,
           const float* __restrict__ v, unsigned short* __restrict__ XS)
{
    const int t  = blockIdx.z;
    const int p  = blockIdx.y;      // 64 panels
    const int kb = blockIdx.x;      // 24
    const float* src = (t == 0) ? q : (t == 1 ? k : v);
    unsigned short* dst = XS + (size_t)t * TEN;

    const int mr = threadIdx.x & 127;
    const int gh = threadIdx.x >> 7;          // 0/1
    const float* s = src + ((size_t)(p * 128 + mr)) * C_DIM + kb * 32 + gh * 16;
    float4 v0 = *(const float4*)(s);
    float4 v1 = *(const float4*)(s + 4);
    float4 v2 = *(const float4*)(s + 8);
    float4 v3 = *(const float4*)(s + 12);
    float f[16] = {v0.x,v0.y,v0.z,v0.w, v1.x,v1.y,v1.z,v1.w,
                   v2.x,v2.y,v2.z,v2.w, v3.x,v3.y,v3.z,v3.w};
    #pragma unroll
    for (int gj = 0; gj < 2; ++gj) {
        int gg = gh * 2 + gj;
        s16x8 h8;
        #pragma unroll
        for (int e = 0; e < 8; ++e)
            h8[e] = (short)f2h(f[gj * 8 + e]);
        size_t a = ((((size_t)p * 24 + kb) * 4 + gg) * 128 + mr) * 8;
        *(s16x8*)(dst + a) = h8;
    }
}

// same for the 4 weight matrices (6 panels each)
__global__ __launch_bounds__(256)
void convW(const float* __restrict__ wq, const float* __restrict__ wk,
           const float* __restrict__ wv, const float* __restrict__ wo,
           unsigned short* __restrict__ WS)
{
    const int t  = blockIdx.z;
    const int p  = blockIdx.y;      // 6 panels
    const int kb = blockIdx.x;      // 24
    const float* src = (t == 0) ? wq : (t == 1 ? wk : (t == 2 ? wv : wo));
    unsigned short* dst = WS + (size_t)t * WN;

    const int mr = threadIdx.x & 127;
    const int gh = threadIdx.x >> 7;
    const float* s = src + ((size_t)(p * 128 + mr)) * C_DIM + kb * 32 + gh * 16;
    float4 v0 = *(const float4*)(s);
    float4 v1 = *(const float4*)(s + 4);
    float4 v2 = *(const float4*)(s + 8);
    float4 v3 = *(const float4*)(s + 12);
    float f[16] = {v0.x,v0.y,v0.z,v0.w, v1.x,v1.y,v1.z,v1.w,
                   v2.x,v2.y,v2.z,v2.w, v3.x,v3.y,v3.z,v3.w};
    #pragma unroll
    for (int gj = 0; gj < 2; ++gj) {
        int gg = gh * 2 + gj;
        s16x8 h8;
        #pragma unroll
        for (int e = 0; e < 8; ++e)
            h8[e] = (short)f2h(f[gj * 8 + e]);
        size_t a = ((((size_t)p * 24 + kb) * 4 + gg) * 128 + mr) * 8;
        *(s16x8*)(dst + a) = h8;
    }
}

// ---------------------------------------------------------------------------
// cos/sin table: 32 pos x 16 freqs
// ---------------------------------------------------------------------------
__global__ void angles512(float2* __restrict__ tab)
{
    int t = threadIdx.x;
    int pos = t >> 4, j = t & 15;
    float ang = (float)pos * exp2f(-(float)j * 0.41524101186092029f);
    float s, c;
    sincosf(ang, &s, &c);
    tab[t] = make_float2(c, s);
}

// ---------------------------------------------------------------------------
// fp16 single-pass MFMA GEMM, BM=128 BN=128 BK=32, 4 waves (2x2), acc[4][4].
// K = 768 -> 24 steps. pk-layout operands -> contiguous 1KB staging issues.
// Counted-vmcnt pipeline: stage(kb+1) stays in flight across the whole iter;
// stage(kb+2) issued after the tail barrier (T3/T4 minimum 2-phase).
// MODE 1 (QKV, z by wgid): z=0/1 fused RoPE -> fp16 head layout; z=2 fp16 (B,N,C)
// MODE 0 (O-proj): fp32 (B,N,C) + bias
// ---------------------------------------------------------------------------
template<int MODE>
__global__ __launch_bounds__(256)
void gemmF(const unsigned short* __restrict__ XQ, const unsigned short* __restrict__ XK,
           const unsigned short* __restrict__ XV,
           const unsigned short* __restrict__ WQ, const unsigned short* __restrict__ WK,
           const unsigned short* __restrict__ WV,
           const int* __restrict__ qpos, const int* __restrict__ kpos,
           const float2* __restrict__ tab,
           unsigned short* __restrict__ OQ, unsigned short* __restrict__ OK_,
           unsigned short* __restrict__ OV,
           const float* __restrict__ bias, float* __restrict__ Of)
{
    __shared__ unsigned short sA[2][4][128][8];   // 16KB
    __shared__ unsigned short sB[2][4][128][8];   // 16KB

    const int tid  = threadIdx.x;
    const int lane = tid & 63;
    const int w    = tid >> 6;
    const int wr   = w >> 1, wc = w & 1;
    const int c    = lane & 15, g = lane >> 4;

    // XCD-chunked, n-fastest block decode (gridDim.x % 8 == 0)
    const int chunk = gridDim.x >> 3;
    const int wgid  = (blockIdx.x & 7) * chunk + (blockIdx.x >> 3);
    int z, m0, n0;
    if (MODE == 1) {
        z = wgid / 384;
        int r = wgid - z * 384;
        m0 = (r / 6) * 128;
        n0 = (r % 6) * 128;
    } else {
        z = 0;
        m0 = (wgid / 6) * 128;
        n0 = (wgid % 6) * 128;
    }

    const unsigned short *Ap, *Bp;
    if (MODE == 0 || z == 0) { Ap = XQ; Bp = WQ; }
    else if (z == 1)         { Ap = XK; Bp = WK; }
    else                     { Ap = XV; Bp = WV; }

    const size_t abase0 = (size_t)(m0 >> 7) * 24 * 4096;
    const size_t bbase0 = (size_t)(n0 >> 7) * 24 * 4096;

    f32x4 acc[4][4] = {};

    // stage K-block kb: A 8KB + B 8KB = 16 issues, 4 per wave
    auto stage = [&](int kb, int buf) {
        #pragma unroll
        for (int t = 0; t < 4; ++t) {
            int is = w * 4 + t;                 // 0..15, wave-uniform
            int sel = is >> 3;                  // 0:A 1:B
            int j   = is & 7;
            int gg  = j >> 1, half = j & 1;
            const unsigned short* srcp =
                (sel ? Bp + bbase0 : Ap + abase0) + (size_t)kb * 4096
                + (size_t)gg * 1024 + (half * 64 + lane) * 8;
            unsigned short* dstp = sel ? &sB[buf][gg][half * 64][0]
                                       : &sA[buf][gg][half * 64][0];
            __builtin_amdgcn_global_load_lds(
                (const __attribute__((address_space(1))) void*)srcp,
                (__attribute__((address_space(3))) void*)dstp,
                16, 0, 0);
        }
    };

    stage(0, 0);
    stage(1, 1);

    for (int kb = 0; kb < 24; ++kb) {
        int buf = kb & 1;
        // wait stage(kb) complete; stage(kb+1)'s 4 loads stay in flight
        if (kb < 23) asm volatile("s_waitcnt vmcnt(4)" ::: "memory");
        else         asm volatile("s_waitcnt vmcnt(0)" ::: "memory");
        __builtin_amdgcn_sched_barrier(0);
        __builtin_amdgcn_s_barrier();
        __builtin_amdgcn_sched_barrier(0);

        f16x8 a[4], b[4];
        #pragma unroll
        for (int mi = 0; mi < 4; ++mi)
            a[mi] = *(const f16x8*)&sA[buf][g][wr * 64 + 16 * mi + c][0];
        #pragma unroll
        for (int ni = 0; ni < 4; ++ni)
            b[ni] = *(const f16x8*)&sB[buf][g][wc * 64 + 16 * ni + c][0];
        __builtin_amdgcn_s_setprio(1);
        #pragma unroll
        for (int mi = 0; mi < 4; ++mi)
            #pragma unroll
            for (int ni = 0; ni < 4; ++ni)
                acc[mi][ni] = __builtin_amdgcn_mfma_f32_16x16x32_f16(a[mi], b[ni], acc[mi][ni], 0, 0, 0);
        __builtin_amdgcn_s_setprio(0);

        // all waves done reading buf -> safe to overwrite with stage(kb+2)
        __builtin_amdgcn_sched_barrier(0);
        __builtin_amdgcn_s_barrier();
        __builtin_amdgcn_sched_barrier(0);
        if (kb + 2 < 24) stage(kb + 2, buf);
    }

    if (MODE == 0) {
        #pragma unroll
        for (int ni = 0; ni < 4; ++ni) {
            int d = n0 + wc * 64 + 16 * ni + c;
            float bv = bias[d];
            #pragma unroll
            for (int mi = 0; mi < 4; ++mi)
                #pragma unroll
                for (int r = 0; r < 4; ++r) {
                    int m = m0 + wr * 64 + 16 * mi + 4 * g + r;
                    Of[(size_t)m * C_DIM + d] = acc[mi][ni][r] + bv;
                }
        }
    } else if (z == 2) {
        // V -> fp16 (B,N,C)
        #pragma unroll
        for (int ni = 0; ni < 4; ++ni) {
            int d = n0 + wc * 64 + 16 * ni + c;
            #pragma unroll
            for (int mi = 0; mi < 4; ++mi)
                #pragma unroll
                for (int r = 0; r < 4; ++r) {
                    int m = m0 + wr * 64 + 16 * mi + 4 * g + r;
                    OV[(size_t)m * C_DIM + d] = f2h(acc[mi][ni][r]);
                }
        }
    } else {
        // Q/K: fused RoPE -> fp16 head layout; wave owns one full head (64 d)
        const int* P = z ? kpos : qpos;
        unsigned short* T = z ? OK_ : OQ;
        const float scale = z ? 1.0f : 0.125f;
        const int hh = (n0 >> 6) + wc;
        #pragma unroll
        for (int mi = 0; mi < 4; ++mi)
            #pragma unroll
            for (int r = 0; r < 4; ++r) {
                int m = m0 + wr * 64 + 16 * mi + 4 * g + r;
                int b = m >> 10, n = m & 1023;
                size_t base = ((size_t)(b * H_DIM + hh) * N_DIM + n) * HD;
                #pragma unroll
                for (int bb = 0; bb < 2; ++bb) {
                    int pos = P[2 * m + bb];
                    float2 cs = tab[pos * 16 + c];
                    float x1 = acc[mi][bb * 2 + 0][r];
                    float x2 = acc[mi][bb * 2 + 1][r];
                    float r1 = (x1 * cs.x - x2 * cs.y) * scale;
                    float r2 = (x2 * cs.x + x1 * cs.y) * scale;
                    T[base + bb * 32 + c]      = f2h(r1);
                    T[base + bb * 32 + 16 + c] = f2h(r2);
                }
            }
    }
}

// ---------------------------------------------------------------------------
// V: (B,N,C) fp16 -> V^T (B,H,64,N) fp16
// ---------------------------------------------------------------------------
__global__ __launch_bounds__(256)
void vtrans(const unsigned short* __restrict__ Vf, unsigned short* __restrict__ Vt)
{
    __shared__ unsigned short T[64][72];
    const int bh = blockIdx.y;
    const int nt = blockIdx.x;
    const int tid = threadIdx.x;
    const int b = bh / H_DIM, h = bh % H_DIM;
    const size_t hb = (size_t)bh * (N_DIM * HD);

    #pragma unroll
    for (int it = 0; it < 2; ++it) {
        int f = tid + it * 256;          // 0..511
        int r = f >> 3;                  // n-row 0..63
        int c8 = (f & 7) * 8;            // d 0..56
        s16x8 v = *(const s16x8*)(Vf + ((size_t)(b * N_DIM + nt * 64 + r)) * C_DIM + h * HD + c8);
        #pragma unroll
        for (int j = 0; j < 8; ++j)
            T[c8 + j][r] = (unsigned short)v[j];
    }
    __syncthreads();
    #pragma unroll
    for (int it = 0; it < 2; ++it) {
        int f = tid + it * 256;
        int d = f >> 3;
        int nn = (f & 7) * 8;
        *(s16x8*)(Vt + hb + (size_t)d * N_DIM + nt * 64 + nn) = *(const s16x8*)&T[d][nn];
    }
}

// ---------------------------------------------------------------------------
// fp16 MFMA flash attention. Emits fp16 x directly in pk layout.
// ---------------------------------------------------------------------------
__global__ __launch_bounds__(256)
void attn_f16(const unsigned short* __restrict__ Qh, const unsigned short* __restrict__ Kh,
              const unsigned short* __restrict__ Vt,
              unsigned short* __restrict__ Xb)
{
    __shared__ _Float16 sK[64][72];
    __shared__ _Float16 sV[64][72];
    __shared__ _Float16 sP[4][16][72];

    const int tid  = threadIdx.x;
    const int lane = tid & 63;
    const int wv   = tid >> 6;
    const int c    = lane & 15;
    const int g    = lane >> 4;

    const int bh = blockIdx.y;
    const int q0 = blockIdx.x * 64;
    const size_t hb = (size_t)bh * (N_DIM * HD);

    const size_t qoff = hb + (size_t)(q0 + wv * 16 + c) * HD;
    f16x8 q0f = *(const f16x8*)(Qh + qoff + 8 * g);
    f16x8 q1f = *(const f16x8*)(Qh + qoff + 32 + 8 * g);

    f32x4 acc[4] = {};
    float m_st = -3.0e38f, l_st = 0.0f;

    for (int kt = 0; kt < 16; ++kt) {
        __syncthreads();
        #pragma unroll
        for (int it = 0; it < 2; ++it) {
            int f = tid + it * 256;      // 0..511
            int row = f >> 3;
            int ch = (f & 7) * 8;
            *(s16x8*)&sK[row][ch] = *(const s16x8*)(Kh + hb + (size_t)(kt * 64 + row) * HD + ch);
            *(s16x8*)&sV[row][ch] = *(const s16x8*)(Vt + hb + (size_t)row * N_DIM + kt * 64 + ch);
        }
        __syncthreads();

        // St = K * Q^T single-pass fp16
        f32x4 s[4] = {};
        __builtin_amdgcn_s_setprio(1);
        #pragma unroll
        for (int st = 0; st < 4; ++st) {
            f16x8 a0 = *(const f16x8*)&sK[16 * st + c][8 * g];
            f16x8 a1 = *(const f16x8*)&sK[16 * st + c][32 + 8 * g];
            s[st] = __builtin_amdgcn_mfma_f32_16x16x32_f16(a0, q0f, s[st], 0, 0, 0);
            s[st] = __builtin_amdgcn_mfma_f32_16x16x32_f16(a1, q1f, s[st], 0, 0, 0);
        }
        __builtin_amdgcn_s_setprio(0);

        // online softmax over k (16 vals/lane for q=c; reduce over 4 g-lanes)
        float pm = -3.0e38f;
        #pragma unroll
        for (int st = 0; st < 4; ++st)
            #pragma unroll
            for (int r = 0; r < 4; ++r)
                pm = fmaxf(pm, s[st][r]);
        pm = fmaxf(pm, __shfl_xor(pm, 16, 64));
        pm = fmaxf(pm, __shfl_xor(pm, 32, 64));
        float mnew = fmaxf(m_st, pm);
        float alpha = __expf(m_st - mnew);
        float p[4][4];
        float rs = 0.0f;
        #pragma unroll
        for (int st = 0; st < 4; ++st)
            #pragma unroll
            for (int r = 0; r < 4; ++r) {
                p[st][r] = __expf(s[st][r] - mnew);
                rs += p[st][r];
            }
        rs += __shfl_xor(rs, 16, 64);
        rs += __shfl_xor(rs, 32, 64);
        l_st = alpha * l_st + rs;
        m_st = mnew;
        #pragma unroll
        for (int sd = 0; sd < 4; ++sd)
            acc[sd] *= alpha;

        // P -> fp16 -> wave-private LDS [q=c][k], k = 16st + 4g + r
        #pragma unroll
        for (int st = 0; st < 4; ++st) {
            unsigned w0 = (unsigned)f2h(p[st][0]) | ((unsigned)f2h(p[st][1]) << 16);
            unsigned w1 = (unsigned)f2h(p[st][2]) | ((unsigned)f2h(p[st][3]) << 16);
            *(uint2*)&sP[wv][c][16 * st + 4 * g] = make_uint2(w0, w1);
        }

        // x^T += V^T * P
        __builtin_amdgcn_s_setprio(1);
        #pragma unroll
        for (int m = 0; m < 2; ++m) {
            f16x8 pb = *(const f16x8*)&sP[wv][c][32 * m + 8 * g];
            #pragma unroll
            for (int sd = 0; sd < 4; ++sd) {
                f16x8 va = *(const f16x8*)&sV[16 * sd + c][32 * m + 8 * g];
                acc[sd] = __builtin_amdgcn_mfma_f32_16x16x32_f16(va, pb, acc[sd], 0, 0, 0);
            }
        }
        __builtin_amdgcn_s_setprio(0);
    }

    // normalize + write fp16 x in pk layout for the O-proj GEMM
    const int b = bh / H_DIM, h = bh % H_DIM;
    const int q = q0 + wv * 16 + c;
    float invl = 1.0f / l_st;
    const int m  = b * N_DIM + q;
    const int p_ = m >> 7, mr = m & 127;
    #pragma unroll
    for (int sd = 0; sd < 4; ++sd) {
        int kdim = h * 64 + 16 * sd + 4 * g;
        int kb = kdim >> 5;
        int gg = (kdim >> 3) & 3;
        int e  = kdim & 7;               // 0 or 4
        size_t a = ((((size_t)p_ * 24 + kb) * 4 + gg) * 128 + mr) * 8 + e;
        unsigned short hs[4];
        #pragma unroll
        for (int r = 0; r < 4; ++r)
            hs[r] = f2h(acc[sd][r] * invl);
        *(uint2*)(Xb + a) =
            make_uint2((unsigned)hs[0] | ((unsigned)hs[1] << 16),
                       (unsigned)hs[2] | ((unsigned)hs[3] << 16));
    }
}

// ---------------------------------------------------------------------------
extern "C" void kernel_launch(void* const* d_in, const int* in_sizes, int n_in,
                              void* d_out, int out_size, void* d_ws, size_t ws_size,
                              hipStream_t stream)
{
    const float* query = (const float*)d_in[0];
    const float* key_  = (const float*)d_in[1];
    const float* value = (const float*)d_in[2];
    const int*   qpos  = (const int*)d_in[3];
    const int*   kpos  = (const int*)d_in[4];
    const float* Wq    = (const float*)d_in[5];
    const float* Wk    = (const float*)d_in[6];
    const float* Wv    = (const float*)d_in[7];
    const float* Wo    = (const float*)d_in[8];
    const float* bo    = (const float*)d_in[9];
    float* out = (float*)d_out;

    unsigned short* XS  = (unsigned short*)d_ws;     // 3 x TEN (pk fp16 q,k,v)
    unsigned short* WS  = XS + 3 * TEN;              // 4 x WN  (pk fp16 Wq..Wo)
    unsigned short* Qh  = WS + 4 * WN;               // fp16 head layout
    unsigned short* Kh  = Qh + TEN;
    unsigned short* Vf  = Kh + TEN;                  // fp16 (B,N,C)
    unsigned short* Vt  = Vf + TEN;                  // fp16 (B,H,64,N)
    unsigned short* Xb  = Vt + TEN;                  // fp16 (pk)
    float2* tab = (float2*)(Xb + TEN);               // 512 float2

    angles512<<<1, 512, 0, stream>>>(tab);
    convX<<<dim3(24, 64, 3), 256, 0, stream>>>(query, key_, value, XS);
    convW<<<dim3(24, 6, 4), 256, 0, stream>>>(Wq, Wk, Wv, Wo, WS);

    gemmF<1><<<dim3(1152), 256, 0, stream>>>(
        XS + 0 * TEN, XS + 1 * TEN, XS + 2 * TEN,
        WS + 0 * WN, WS + 1 * WN, WS + 2 * WN,
        qpos, kpos, tab, Qh, Kh, Vf, nullptr, nullptr);

    vtrans<<<dim3(N_DIM / 64, BH), 256, 0, stream>>>(Vf, Vt);

    attn_f16<<<dim3(N_DIM / 64, BH), 256, 0, stream>>>(Qh, Kh, Vt, Xb);

    gemmF<0><<<dim3(384), 256, 0, stream>>>(
        Xb, nullptr, nullptr,
        WS + 3 * WN, nullptr, nullptr,
        nullptr, nullptr, nullptr, nullptr, nullptr, nullptr, bo, out);
}